// Round 1
// baseline (233.131 us; speedup 1.0000x reference)
//
#include <hip/hip_runtime.h>
#include <hip/hip_bf16.h>

#define BATCH 16
#define SEQL  4096
#define NH    16
#define HD    64
#define HID   1024
#define NCHUNK 8
#define CHUNK  (SEQL / NCHUNK)   // 512
#define KV_ELEMS (BATCH * NH * SEQL * HD)  // 67108864

typedef float f4 __attribute__((ext_vector_type(4)));

// ---------------------------------------------------------------------------
// Kernel 1/4: partial projection  part[y][z][b][o] = sum over k-quarter z of
//             x[b][k] * W[o][k].   grid = (16 o-tiles, nW, 4 k-quarters)
// ---------------------------------------------------------------------------
__global__ __launch_bounds__(256) void proj_partial(
    const float* __restrict__ x,    // [16][1024]
    const float* __restrict__ W0,
    const float* __restrict__ W1,
    const float* __restrict__ W2,
    float* __restrict__ part)       // [gridDim.y][4][16][1024]
{
    __shared__ float xs[BATCH * HID];   // 64 KB
    const int t = threadIdx.x;
    for (int i = t; i < BATCH * HID; i += 256) xs[i] = x[i];
    __syncthreads();

    const float* W = (blockIdx.y == 0) ? W0 : ((blockIdx.y == 1) ? W1 : W2);
    const int otile = blockIdx.x;
    const int z     = blockIdx.z;
    const int og = t & 15;          // 16 o-groups of 4 columns
    const int sl = t >> 4;          // 16 k-sub-slices of 16
    const int obase = otile * 64 + og * 4;
    const int kbase = z * 256 + sl * 16;

    float acc[4][BATCH];
    #pragma unroll
    for (int oi = 0; oi < 4; ++oi)
        #pragma unroll
        for (int b = 0; b < BATCH; ++b) acc[oi][b] = 0.f;

    #pragma unroll
    for (int kk = 0; kk < 16; kk += 4) {
        const int k = kbase + kk;
        f4 w4[4];
        #pragma unroll
        for (int oi = 0; oi < 4; ++oi)
            w4[oi] = *(const f4*)&W[(size_t)(obase + oi) * HID + k];
        #pragma unroll
        for (int b = 0; b < BATCH; ++b) {
            f4 h4 = *(const f4*)&xs[b * HID + k];
            #pragma unroll
            for (int oi = 0; oi < 4; ++oi)
                acc[oi][b] += w4[oi].x * h4.x + w4[oi].y * h4.y
                            + w4[oi].z * h4.z + w4[oi].w * h4.w;
        }
    }

    __syncthreads();            // done reading xs, reuse as reduction buffer
    float* red = xs;            // red[sl][og][oi][b]
    #pragma unroll
    for (int oi = 0; oi < 4; ++oi)
        #pragma unroll
        for (int b = 0; b < BATCH; ++b)
            red[((sl * 16 + og) * 4 + oi) * 16 + b] = acc[oi][b];
    __syncthreads();

    // 64 o  x 16 b = 1024 outputs; 4 per thread, summed over 16 sub-slices
    #pragma unroll
    for (int u = 0; u < 4; ++u) {
        const int idx = t * 4 + u;       // 0..1023
        const int o_local = idx >> 4;    // 0..63
        const int b = idx & 15;
        const int ogg = o_local >> 2, oii = o_local & 3;
        float s = 0.f;
        #pragma unroll
        for (int s2 = 0; s2 < 16; ++s2)
            s += red[((s2 * 16 + ogg) * 4 + oii) * 16 + b];
        part[(size_t)(blockIdx.y * 4 + z) * (BATCH * HID)
             + b * HID + otile * 64 + o_local] = s;
    }
}

// ---------------------------------------------------------------------------
// Kernel 2: sum 4 k-quarter partials + bias -> qkv[3][16][1024]
// ---------------------------------------------------------------------------
__global__ __launch_bounds__(256) void reduce_qkv(
    const float* __restrict__ part,
    const float* __restrict__ bq, const float* __restrict__ bk,
    const float* __restrict__ bv, float* __restrict__ qkv)
{
    const int i = blockIdx.x * 256 + threadIdx.x;   // 0..49151
    const int w = i >> 14;
    const int rem = i & 16383;
    const int o = rem & (HID - 1);
    float s = 0.f;
    #pragma unroll
    for (int z = 0; z < 4; ++z)
        s += part[(size_t)(w * 4 + z) * (BATCH * HID) + rem];
    const float* bias = (w == 0) ? bq : ((w == 1) ? bk : bv);
    qkv[i] = s + bias[o];
}

// ---------------------------------------------------------------------------
// Kernel 3: fused cache-copy + flash-decode partial attention.
//   grid = (256 (b,h) pairs, 8 L-chunks), block = 256 (16 groups x 16 lanes)
//   Each group streams rows: copy K/V rows to output caches (substituting the
//   new row at pos[b]) while accumulating online-softmax state.
// ---------------------------------------------------------------------------
__global__ __launch_bounds__(256) void attn_fused(
    const float* __restrict__ qkv,     // q @0, k @16384, v @32768
    const float* __restrict__ past_k,
    const float* __restrict__ past_v,
    const float* __restrict__ mask,    // [16][4096]
    const int*   __restrict__ cpos,    // [16]
    float* __restrict__ kout,
    float* __restrict__ vout,
    float* __restrict__ part)          // [256][8][66]
{
    const int bh = blockIdx.x;         // 0..255
    const int c  = blockIdx.y;         // 0..7
    const int b  = bh >> 4;
    const int h  = bh & 15;
    const int t  = threadIdx.x;
    const int g  = t >> 4;             // group 0..15
    const int j  = t & 15;             // lane in group

    const int pos = cpos[b];
    const int qoff = b * HID + h * HD + j * 4;
    const f4 q4 = *(const f4*)&qkv[qoff];
    const f4 kn4 = *(const f4*)&qkv[BATCH * HID + qoff];
    const f4 vn4 = *(const f4*)&qkv[2 * BATCH * HID + qoff];

    const size_t base = (size_t)bh * SEQL * HD;
    const float scale = 0.125f;   // 1/sqrt(64)

    float m = -INFINITY, l = 0.f;
    f4 a4 = {0.f, 0.f, 0.f, 0.f};

    const int r_end = c * CHUNK + CHUNK;
    for (int r = c * CHUNK + g; r < r_end; r += 16) {
        const size_t off = base + (size_t)r * HD + j * 4;
        f4 k4 = __builtin_nontemporal_load((const f4*)(past_k + off));
        f4 v4 = __builtin_nontemporal_load((const f4*)(past_v + off));
        if (r == pos) { k4 = kn4; v4 = vn4; }
        __builtin_nontemporal_store(k4, (f4*)(kout + off));
        __builtin_nontemporal_store(v4, (f4*)(vout + off));

        float d = k4.x * q4.x + k4.y * q4.y + k4.z * q4.z + k4.w * q4.w;
        d += __shfl_xor(d, 1);
        d += __shfl_xor(d, 2);
        d += __shfl_xor(d, 4);
        d += __shfl_xor(d, 8);

        const float am = mask[b * SEQL + r];
        const float s = (am > 0.f) ? d * scale : -3.4028235e38f;

        const float mnew = fmaxf(m, s);
        const float fac = __expf(m - mnew);
        const float p   = __expf(s - mnew);
        l = l * fac + p;
        a4.x = a4.x * fac + p * v4.x;
        a4.y = a4.y * fac + p * v4.y;
        a4.z = a4.z * fac + p * v4.z;
        a4.w = a4.w * fac + p * v4.w;
        m = mnew;
    }

    // merge the 16 group states
    __shared__ float sm[16], sl[16];
    __shared__ float sa[16][64];
    if (j == 0) { sm[g] = m; sl[g] = l; }
    *(f4*)&sa[g][j * 4] = a4;
    __syncthreads();

    if (t < 64) {
        float M = -INFINITY;
        #pragma unroll
        for (int gg = 0; gg < 16; ++gg) M = fmaxf(M, sm[gg]);
        float Ls = 0.f, A = 0.f;
        #pragma unroll
        for (int gg = 0; gg < 16; ++gg) {
            const float wgt = __expf(sm[gg] - M);
            Ls += sl[gg] * wgt;
            A  += sa[gg][t] * wgt;
        }
        float* pr = part + ((size_t)bh * NCHUNK + c) * 66;
        if (t == 0) { pr[0] = M; pr[1] = Ls; }
        pr[2 + t] = A;
    }
}

// ---------------------------------------------------------------------------
// Kernel 4: merge chunk partials -> ctx[b][h*64+d]
// ---------------------------------------------------------------------------
__global__ __launch_bounds__(64) void merge_ctx(
    const float* __restrict__ part, float* __restrict__ ctx)
{
    const int bh = blockIdx.x;
    const int d = threadIdx.x;
    float M = -INFINITY;
    #pragma unroll
    for (int cc = 0; cc < NCHUNK; ++cc)
        M = fmaxf(M, part[((size_t)bh * NCHUNK + cc) * 66]);
    float Ls = 0.f, A = 0.f;
    #pragma unroll
    for (int cc = 0; cc < NCHUNK; ++cc) {
        const float* pr = part + ((size_t)bh * NCHUNK + cc) * 66;
        const float wgt = __expf(pr[0] - M);
        Ls += pr[1] * wgt;
        A  += pr[2 + d] * wgt;
    }
    ctx[bh * HD + d] = A / Ls;
}

// ---------------------------------------------------------------------------
// Kernel 5: sum 4 k-quarter partials + bo -> attn_output
// ---------------------------------------------------------------------------
__global__ __launch_bounds__(256) void reduce_out(
    const float* __restrict__ part, const float* __restrict__ bo,
    float* __restrict__ out)
{
    const int i = blockIdx.x * 256 + threadIdx.x;   // 0..16383
    const int o = i & (HID - 1);
    float s = 0.f;
    #pragma unroll
    for (int z = 0; z < 4; ++z)
        s += part[(size_t)z * (BATCH * HID) + i];
    out[i] = s + bo[o];
}

extern "C" void kernel_launch(void* const* d_in, const int* in_sizes, int n_in,
                              void* d_out, int out_size, void* d_ws, size_t ws_size,
                              hipStream_t stream) {
    const float* hs   = (const float*)d_in[0];
    const float* pk   = (const float*)d_in[1];
    const float* pv   = (const float*)d_in[2];
    const float* mask = (const float*)d_in[3];
    const int*   cpos = (const int*)d_in[4];
    const float* Wq   = (const float*)d_in[5];
    const float* bq   = (const float*)d_in[6];
    const float* Wk   = (const float*)d_in[7];
    const float* bk   = (const float*)d_in[8];
    const float* Wv   = (const float*)d_in[9];
    const float* bv   = (const float*)d_in[10];
    const float* Wo   = (const float*)d_in[11];
    const float* bo   = (const float*)d_in[12];

    float* out_attn = (float*)d_out;                 // 16384
    float* kout = out_attn + BATCH * HID;            // 67108864
    float* vout = kout + KV_ELEMS;                   // 67108864

    float* ws    = (float*)d_ws;
    float* qkv   = ws;              // 49152
    float* ctx   = ws + 49152;      // 16384
    float* apart = ws + 65536;      // 256*8*66 = 135168
    float* ppart = ws + 200704;     // 3*4*16384 = 196608

    // q,k,v projections (k-split, two-stage deterministic reduce)
    proj_partial<<<dim3(16, 3, 4), 256, 0, stream>>>(hs, Wq, Wk, Wv, ppart);
    reduce_qkv<<<dim3(192), 256, 0, stream>>>(ppart, bq, bk, bv, qkv);

    // fused cache-copy + flash-decode attention
    attn_fused<<<dim3(256, NCHUNK), 256, 0, stream>>>(qkv, pk, pv, mask, cpos,
                                                      kout, vout, apart);
    merge_ctx<<<dim3(256), 64, 0, stream>>>(apart, ctx);

    // output projection
    proj_partial<<<dim3(16, 1, 4), 256, 0, stream>>>(ctx, Wo, Wo, Wo, ppart);
    reduce_out<<<dim3(64), 256, 0, stream>>>(ppart, bo, out_attn);
}

// Round 2
// 229.649 us; speedup vs baseline: 1.0152x; 1.0152x over previous
//
#include <hip/hip_runtime.h>
#include <hip/hip_bf16.h>

#define BATCH 16
#define SEQL  4096
#define NH    16
#define HD    64
#define HID   1024
#define NCHUNK 8
#define CHUNK  (SEQL / NCHUNK)   // 512
#define KV_ELEMS (BATCH * NH * SEQL * HD)  // 67108864
#define PSTRIDE 68               // partial record: [0]=L, [1..64]=A
#define C2 0.1803368801f         // 0.125 * log2(e)

typedef float f4 __attribute__((ext_vector_type(4)));

// ---------------------------------------------------------------------------
// Kernel 1: partial projection  part[y][z][b][o] = sum over k-quarter z of
//           x[b][k] * W[o][k].   grid = (16 o-tiles, nW, 4 k-quarters)
// ---------------------------------------------------------------------------
__global__ __launch_bounds__(256) void proj_partial(
    const float* __restrict__ x,    // [16][1024]
    const float* __restrict__ W0,
    const float* __restrict__ W1,
    const float* __restrict__ W2,
    float* __restrict__ part)       // [gridDim.y][4][16][1024]
{
    __shared__ float xs[BATCH * HID];   // 64 KB
    const int t = threadIdx.x;
    for (int i = t; i < BATCH * HID; i += 256) xs[i] = x[i];
    __syncthreads();

    const float* W = (blockIdx.y == 0) ? W0 : ((blockIdx.y == 1) ? W1 : W2);
    const int otile = blockIdx.x;
    const int z     = blockIdx.z;
    const int og = t & 15;          // 16 o-groups of 4 columns
    const int sl = t >> 4;          // 16 k-sub-slices of 16
    const int obase = otile * 64 + og * 4;
    const int kbase = z * 256 + sl * 16;

    float acc[4][BATCH];
    #pragma unroll
    for (int oi = 0; oi < 4; ++oi)
        #pragma unroll
        for (int b = 0; b < BATCH; ++b) acc[oi][b] = 0.f;

    #pragma unroll
    for (int kk = 0; kk < 16; kk += 4) {
        const int k = kbase + kk;
        f4 w4[4];
        #pragma unroll
        for (int oi = 0; oi < 4; ++oi)
            w4[oi] = *(const f4*)&W[(size_t)(obase + oi) * HID + k];
        #pragma unroll
        for (int b = 0; b < BATCH; ++b) {
            f4 h4 = *(const f4*)&xs[b * HID + k];
            #pragma unroll
            for (int oi = 0; oi < 4; ++oi)
                acc[oi][b] += w4[oi].x * h4.x + w4[oi].y * h4.y
                            + w4[oi].z * h4.z + w4[oi].w * h4.w;
        }
    }

    __syncthreads();            // done reading xs, reuse as reduction buffer
    float* red = xs;            // red[sl][og][oi][b]
    #pragma unroll
    for (int oi = 0; oi < 4; ++oi)
        #pragma unroll
        for (int b = 0; b < BATCH; ++b)
            red[((sl * 16 + og) * 4 + oi) * 16 + b] = acc[oi][b];
    __syncthreads();

    #pragma unroll
    for (int u = 0; u < 4; ++u) {
        const int idx = t * 4 + u;       // 0..1023
        const int o_local = idx >> 4;    // 0..63
        const int b = idx & 15;
        const int ogg = o_local >> 2, oii = o_local & 3;
        float s = 0.f;
        #pragma unroll
        for (int s2 = 0; s2 < 16; ++s2)
            s += red[((s2 * 16 + ogg) * 4 + oii) * 16 + b];
        part[(size_t)(blockIdx.y * 4 + z) * (BATCH * HID)
             + b * HID + otile * 64 + o_local] = s;
    }
}

// ---------------------------------------------------------------------------
// Kernel 2: sum 4 k-quarter partials + bias -> qkv[3][16][1024]
// ---------------------------------------------------------------------------
__global__ __launch_bounds__(256) void reduce_qkv(
    const float* __restrict__ part,
    const float* __restrict__ bq, const float* __restrict__ bk,
    const float* __restrict__ bv, float* __restrict__ qkv)
{
    const int i = blockIdx.x * 256 + threadIdx.x;   // 0..49151
    const int w = i >> 14;
    const int rem = i & 16383;
    const int o = rem & (HID - 1);
    float s = 0.f;
    #pragma unroll
    for (int z = 0; z < 4; ++z)
        s += part[(size_t)(w * 4 + z) * (BATCH * HID) + rem];
    const float* bias = (w == 0) ? bq : ((w == 1) ? bk : bv);
    qkv[i] = s + bias[o];
}

// ---------------------------------------------------------------------------
// Kernel 3: fused cache-copy + flash-decode partial attention (pure stream).
//   grid = (256 (b,h) pairs, 8 L-chunks), block = 256 (16 groups x 16 lanes)
//   Streams STALE rows (no pos substitution -> no select, fewer regs, no
//   serial max chain). Row `pos` is corrected exactly in merge_fix.
//   Unroll x4: 12 loads in flight per wait -> latency hidden at ~6 waves/SIMD.
// ---------------------------------------------------------------------------
__global__ __launch_bounds__(256, 8) void attn_fused(
    const float* __restrict__ qkv,     // q @0
    const float* __restrict__ past_k,
    const float* __restrict__ past_v,
    const float* __restrict__ mask,    // [16][4096]
    float* __restrict__ kout,
    float* __restrict__ vout,
    float* __restrict__ part)          // [256][8][PSTRIDE]
{
    const int bh = blockIdx.x;         // 0..255
    const int c  = blockIdx.y;         // 0..7
    const int b  = bh >> 4;
    const int h  = bh & 15;
    const int t  = threadIdx.x;
    const int g  = t >> 4;             // group 0..15
    const int j  = t & 15;             // lane in group

    const f4 q4 = *(const f4*)&qkv[b * HID + h * HD + j * 4];

    const size_t base = (size_t)bh * SEQL * HD;
    const float* __restrict__ pkb = past_k + base;
    const float* __restrict__ pvb = past_v + base;
    float* __restrict__ kob = kout + base;
    float* __restrict__ vob = vout + base;
    const float* __restrict__ mrow = mask + b * SEQL;

    float l = 0.f;
    f4 a4 = {0.f, 0.f, 0.f, 0.f};

    int r = c * CHUNK + g;
    #pragma unroll 1
    for (int it = 0; it < CHUNK / 64; ++it) {   // 8 iterations
        f4 k4[4], v4[4];
        float am[4];
        int ro[4];
        #pragma unroll
        for (int u = 0; u < 4; ++u) {
            const int rr = r + u * 16;
            ro[u] = rr * HD + (j << 2);
            k4[u] = __builtin_nontemporal_load((const f4*)(pkb + ro[u]));
            v4[u] = __builtin_nontemporal_load((const f4*)(pvb + ro[u]));
            am[u] = mrow[rr];
        }
        #pragma unroll
        for (int u = 0; u < 4; ++u) {
            __builtin_nontemporal_store(k4[u], (f4*)(kob + ro[u]));
            __builtin_nontemporal_store(v4[u], (f4*)(vob + ro[u]));
        }
        #pragma unroll
        for (int u = 0; u < 4; ++u) {
            float d = k4[u].x * q4.x + k4[u].y * q4.y
                    + k4[u].z * q4.z + k4[u].w * q4.w;
            d += __shfl_xor(d, 1);
            d += __shfl_xor(d, 2);
            d += __shfl_xor(d, 4);
            d += __shfl_xor(d, 8);
            float p = exp2f(d * C2);
            p = (am[u] > 0.f) ? p : 0.f;
            l += p;
            a4.x += p * v4[u].x;
            a4.y += p * v4[u].y;
            a4.z += p * v4[u].z;
            a4.w += p * v4[u].w;
        }
        r += 64;
    }

    // merge the 16 group states (straight sums — fixed-shift softmax)
    __shared__ float sl_[16];
    __shared__ float sa[16][64];
    if (j == 0) sl_[g] = l;
    *(f4*)&sa[g][j * 4] = a4;
    __syncthreads();

    float* pr = part + ((size_t)bh * NCHUNK + c) * PSTRIDE;
    if (t < 64) {
        float A = 0.f;
        #pragma unroll
        for (int gg = 0; gg < 16; ++gg) A += sa[gg][t];
        pr[1 + t] = A;
    } else if (t == 64) {
        float L = 0.f;
        #pragma unroll
        for (int gg = 0; gg < 16; ++gg) L += sl_[gg];
        pr[0] = L;
    }
}

// ---------------------------------------------------------------------------
// Kernel 4: per (b,h): overwrite cache row `pos` with the new k/v, correct
//           the affected chunk partial (remove stale row term, add new one),
//           then merge all chunk partials -> ctx. Block = 64 threads = 1 wave.
// ---------------------------------------------------------------------------
__global__ __launch_bounds__(64) void merge_fix(
    const float* __restrict__ qkv,
    const float* __restrict__ past_k,
    const float* __restrict__ past_v,
    const float* __restrict__ mask,
    const int*   __restrict__ cpos,
    float* __restrict__ kout,
    float* __restrict__ vout,
    const float* __restrict__ part,
    float* __restrict__ ctx)
{
    const int bh = blockIdx.x;
    const int b = bh >> 4, h = bh & 15;
    const int t = threadIdx.x;          // 0..63 (= head dim)
    const int pos = cpos[b];

    const size_t rowoff = (size_t)bh * SEQL * HD + (size_t)pos * HD + t;
    const int qo = b * HID + h * HD + t;
    const float qd  = qkv[qo];
    const float knd = qkv[BATCH * HID + qo];
    const float vnd = qkv[2 * BATCH * HID + qo];
    const float ksd = past_k[rowoff];
    const float vsd = past_v[rowoff];

    // overwrite caches at pos with the new row
    kout[rowoff] = knd;
    vout[rowoff] = vnd;

    // stale & new scores via full-wave reduce
    float dst = qd * ksd, dnw = qd * knd;
    #pragma unroll
    for (int sh = 1; sh < 64; sh <<= 1) {
        dst += __shfl_xor(dst, sh);
        dnw += __shfl_xor(dnw, sh);
    }
    const float am = mask[b * SEQL + pos];
    float ps = 0.f, pn = 0.f;
    if (am > 0.f) { ps = exp2f(dst * C2); pn = exp2f(dnw * C2); }

    const int cc0 = pos / CHUNK;
    float L = 0.f, A = 0.f;
    #pragma unroll
    for (int cc = 0; cc < NCHUNK; ++cc) {
        const float* pr = part + ((size_t)bh * NCHUNK + cc) * PSTRIDE;
        float Lc = pr[0];
        float Ac = pr[1 + t];
        if (cc == cc0) { Lc += pn - ps; Ac += pn * vnd - ps * vsd; }
        L += Lc;
        A += Ac;
    }
    ctx[bh * HD + t] = A / L;
}

// ---------------------------------------------------------------------------
// Kernel 5: sum 4 k-quarter partials + bo -> attn_output
// ---------------------------------------------------------------------------
__global__ __launch_bounds__(256) void reduce_out(
    const float* __restrict__ part, const float* __restrict__ bo,
    float* __restrict__ out)
{
    const int i = blockIdx.x * 256 + threadIdx.x;   // 0..16383
    const int o = i & (HID - 1);
    float s = 0.f;
    #pragma unroll
    for (int z = 0; z < 4; ++z)
        s += part[(size_t)z * (BATCH * HID) + i];
    out[i] = s + bo[o];
}

extern "C" void kernel_launch(void* const* d_in, const int* in_sizes, int n_in,
                              void* d_out, int out_size, void* d_ws, size_t ws_size,
                              hipStream_t stream) {
    const float* hs   = (const float*)d_in[0];
    const float* pk   = (const float*)d_in[1];
    const float* pv   = (const float*)d_in[2];
    const float* mask = (const float*)d_in[3];
    const int*   cpos = (const int*)d_in[4];
    const float* Wq   = (const float*)d_in[5];
    const float* bq   = (const float*)d_in[6];
    const float* Wk   = (const float*)d_in[7];
    const float* bk   = (const float*)d_in[8];
    const float* Wv   = (const float*)d_in[9];
    const float* bv   = (const float*)d_in[10];
    const float* Wo   = (const float*)d_in[11];
    const float* bo   = (const float*)d_in[12];

    float* out_attn = (float*)d_out;                 // 16384
    float* kout = out_attn + BATCH * HID;            // 67108864
    float* vout = kout + KV_ELEMS;                   // 67108864

    float* ws    = (float*)d_ws;
    float* qkv   = ws;              // 49152
    float* ctx   = ws + 49152;      // 16384
    float* apart = ws + 65536;      // 256*8*68 = 139264
    float* ppart = ws + 204800;     // 3*4*16384 = 196608

    // q,k,v projections (k-split, two-stage deterministic reduce)
    proj_partial<<<dim3(16, 3, 4), 256, 0, stream>>>(hs, Wq, Wk, Wv, ppart);
    reduce_qkv<<<dim3(192), 256, 0, stream>>>(ppart, bq, bk, bv, qkv);

    // fused cache-copy + flash-decode attention (pure stream, stale row pos)
    attn_fused<<<dim3(256, NCHUNK), 256, 0, stream>>>(qkv, pk, pv, mask,
                                                      kout, vout, apart);
    // fix row pos (cache + partials) and merge chunks
    merge_fix<<<dim3(256), 64, 0, stream>>>(qkv, pk, pv, mask, cpos,
                                            kout, vout, apart, ctx);

    // output projection
    proj_partial<<<dim3(16, 1, 4), 256, 0, stream>>>(ctx, Wo, Wo, Wo, ppart);
    reduce_out<<<dim3(64), 256, 0, stream>>>(ppart, bo, out_attn);
}

// Round 3
// 222.835 us; speedup vs baseline: 1.0462x; 1.0306x over previous
//
#include <hip/hip_runtime.h>
#include <hip/hip_bf16.h>

#define BATCH 16
#define SEQL  4096
#define NH    16
#define HD    64
#define HID   1024
#define NCHUNK 8
#define CHUNK  (SEQL / NCHUNK)   // 512
#define KV_ELEMS (BATCH * NH * SEQL * HD)  // 67108864
#define PSTRIDE 68               // partial record: [0]=L, [1..64]=A
#define C2 0.1803368801f         // 0.125 * log2(e)

typedef float f4 __attribute__((ext_vector_type(4)));

// ---------------------------------------------------------------------------
// Kernel 1: single-pass batched GEMV.  out[w][b][o] = x[b][:] . W[o][:] + bias
//   grid = nW*256 blocks; block = 256 (4 output cols x 64 lanes).
//   Full K per wave (coalesced 4KB W-row reads), shfl-tree reduce -> exact,
//   deterministic, no cross-block k-split.
// ---------------------------------------------------------------------------
__global__ __launch_bounds__(256) void gemv3(
    const float* __restrict__ x,    // [16][1024]
    const float* __restrict__ W0, const float* __restrict__ W1,
    const float* __restrict__ W2,
    const float* __restrict__ b0, const float* __restrict__ b1,
    const float* __restrict__ b2,
    float* __restrict__ out)        // [nW][16][1024]
{
    __shared__ float xs[BATCH * HID];   // 64 KB
    const int t = threadIdx.x;
    {
        const f4* src = (const f4*)x;
        f4* dst = (f4*)xs;
        #pragma unroll
        for (int i = 0; i < (BATCH * HID / 4) / 256; ++i)
            dst[t + i * 256] = src[t + i * 256];
    }
    __syncthreads();

    const int which = blockIdx.x >> 8;
    const int ob    = (blockIdx.x & 255) << 2;
    const float* W    = (which == 0) ? W0 : ((which == 1) ? W1 : W2);
    const float* bias = (which == 0) ? b0 : ((which == 1) ? b1 : b2);
    const int col = t >> 6, lane = t & 63;
    const int o = ob + col;
    const float* wrow = W + (size_t)o * HID;

    float acc[BATCH];
    #pragma unroll
    for (int b = 0; b < BATCH; ++b) acc[b] = 0.f;

    #pragma unroll
    for (int i = 0; i < 4; ++i) {
        const int k = (lane << 2) + (i << 8);
        const f4 w4 = *(const f4*)&wrow[k];
        #pragma unroll
        for (int b = 0; b < BATCH; ++b) {
            const f4 h4 = *(const f4*)&xs[b * HID + k];
            acc[b] += w4.x * h4.x + w4.y * h4.y + w4.z * h4.z + w4.w * h4.w;
        }
    }

    #pragma unroll
    for (int b = 0; b < BATCH; ++b) {
        #pragma unroll
        for (int sh = 1; sh < 64; sh <<= 1)
            acc[b] += __shfl_xor(acc[b], sh);
    }
    if (lane == 0) {
        const float bb = bias[o];
        #pragma unroll
        for (int b = 0; b < BATCH; ++b)
            out[which * (BATCH * HID) + b * HID + o] = acc[b] + bb;
    }
}

// ---------------------------------------------------------------------------
// Kernel 2: fused cache-copy + flash-decode partial attention (pure stream).
//   grid = (256 (b,h) pairs, 8 L-chunks), block = 256 (16 groups x 16 lanes)
//   Streams STALE rows; row `pos` corrected exactly in merge_fix.
//   Unroll x2 -> ~45 VGPR -> guaranteed 8 waves/SIMD, all blocks co-resident.
// ---------------------------------------------------------------------------
__global__ __launch_bounds__(256, 8) void attn_fused(
    const float* __restrict__ qkv,     // q @0
    const float* __restrict__ past_k,
    const float* __restrict__ past_v,
    const float* __restrict__ mask,    // [16][4096]
    float* __restrict__ kout,
    float* __restrict__ vout,
    float* __restrict__ part)          // [256][8][PSTRIDE]
{
    const int bh = blockIdx.x;         // 0..255
    const int c  = blockIdx.y;         // 0..7
    const int b  = bh >> 4;
    const int h  = bh & 15;
    const int t  = threadIdx.x;
    const int g  = t >> 4;             // group 0..15
    const int j  = t & 15;             // lane in group

    const f4 q4 = *(const f4*)&qkv[b * HID + h * HD + (j << 2)];

    const size_t base = (size_t)bh * (SEQL * HD);
    const float* __restrict__ pkb = past_k + base;
    const float* __restrict__ pvb = past_v + base;
    float* __restrict__ kob = kout + base;
    float* __restrict__ vob = vout + base;
    const float* __restrict__ mrow = mask + b * SEQL;

    float l = 0.f;
    f4 a4 = {0.f, 0.f, 0.f, 0.f};

    int r0  = c * CHUNK + g;
    int off = r0 * HD + (j << 2);      // 32-bit offset off uniform base

    #pragma unroll 1
    for (int it = 0; it < CHUNK / 32; ++it) {   // 16 iterations, 2 rows each
        const int o1 = off + 16 * HD;
        const f4 k0 = __builtin_nontemporal_load((const f4*)(pkb + off));
        const f4 v0 = __builtin_nontemporal_load((const f4*)(pvb + off));
        const f4 k1 = __builtin_nontemporal_load((const f4*)(pkb + o1));
        const f4 v1 = __builtin_nontemporal_load((const f4*)(pvb + o1));
        const float am0 = mrow[r0];
        const float am1 = mrow[r0 + 16];
        __builtin_nontemporal_store(k0, (f4*)(kob + off));
        __builtin_nontemporal_store(v0, (f4*)(vob + off));
        __builtin_nontemporal_store(k1, (f4*)(kob + o1));
        __builtin_nontemporal_store(v1, (f4*)(vob + o1));

        float d0 = k0.x * q4.x + k0.y * q4.y + k0.z * q4.z + k0.w * q4.w;
        d0 += __shfl_xor(d0, 1);
        d0 += __shfl_xor(d0, 2);
        d0 += __shfl_xor(d0, 4);
        d0 += __shfl_xor(d0, 8);
        float p0 = exp2f(d0 * C2);
        p0 = (am0 > 0.f) ? p0 : 0.f;
        l += p0;
        a4.x += p0 * v0.x; a4.y += p0 * v0.y;
        a4.z += p0 * v0.z; a4.w += p0 * v0.w;

        float d1 = k1.x * q4.x + k1.y * q4.y + k1.z * q4.z + k1.w * q4.w;
        d1 += __shfl_xor(d1, 1);
        d1 += __shfl_xor(d1, 2);
        d1 += __shfl_xor(d1, 4);
        d1 += __shfl_xor(d1, 8);
        float p1 = exp2f(d1 * C2);
        p1 = (am1 > 0.f) ? p1 : 0.f;
        l += p1;
        a4.x += p1 * v1.x; a4.y += p1 * v1.y;
        a4.z += p1 * v1.z; a4.w += p1 * v1.w;

        off += 32 * HD;
        r0  += 32;
    }

    // merge the 16 group states (straight sums — fixed-shift softmax)
    __shared__ float sl_[16];
    __shared__ float sa[16][64];
    if (j == 0) sl_[g] = l;
    *(f4*)&sa[g][(j << 2)] = a4;
    __syncthreads();

    float* pr = part + ((size_t)bh * NCHUNK + c) * PSTRIDE;
    if (t < 64) {
        float A = 0.f;
        #pragma unroll
        for (int gg = 0; gg < 16; ++gg) A += sa[gg][t];
        pr[1 + t] = A;
    } else if (t == 64) {
        float L = 0.f;
        #pragma unroll
        for (int gg = 0; gg < 16; ++gg) L += sl_[gg];
        pr[0] = L;
    }
}

// ---------------------------------------------------------------------------
// Kernel 3: per (b,h): overwrite cache row `pos` with the new k/v, correct
//           the affected chunk partial (remove stale row term, add new one),
//           then merge all chunk partials -> ctx. Block = 64 threads = 1 wave.
// ---------------------------------------------------------------------------
__global__ __launch_bounds__(64) void merge_fix(
    const float* __restrict__ qkv,
    const float* __restrict__ past_k,
    const float* __restrict__ past_v,
    const float* __restrict__ mask,
    const int*   __restrict__ cpos,
    float* __restrict__ kout,
    float* __restrict__ vout,
    const float* __restrict__ part,
    float* __restrict__ ctx)
{
    const int bh = blockIdx.x;
    const int b = bh >> 4, h = bh & 15;
    const int t = threadIdx.x;          // 0..63 (= head dim)
    const int pos = cpos[b];

    const size_t rowoff = (size_t)bh * (SEQL * HD) + (size_t)pos * HD + t;
    const int qo = b * HID + h * HD + t;
    const float qd  = qkv[qo];
    const float knd = qkv[BATCH * HID + qo];
    const float vnd = qkv[2 * BATCH * HID + qo];
    const float ksd = past_k[rowoff];
    const float vsd = past_v[rowoff];

    // overwrite caches at pos with the new row
    kout[rowoff] = knd;
    vout[rowoff] = vnd;

    // stale & new scores via full-wave reduce
    float dst = qd * ksd, dnw = qd * knd;
    #pragma unroll
    for (int sh = 1; sh < 64; sh <<= 1) {
        dst += __shfl_xor(dst, sh);
        dnw += __shfl_xor(dnw, sh);
    }
    const float am = mask[b * SEQL + pos];
    float ps = 0.f, pn = 0.f;
    if (am > 0.f) { ps = exp2f(dst * C2); pn = exp2f(dnw * C2); }

    const int cc0 = pos / CHUNK;
    float L = 0.f, A = 0.f;
    #pragma unroll
    for (int cc = 0; cc < NCHUNK; ++cc) {
        const float* pr = part + ((size_t)bh * NCHUNK + cc) * PSTRIDE;
        float Lc = pr[0];
        float Ac = pr[1 + t];
        if (cc == cc0) { Lc += pn - ps; Ac += pn * vnd - ps * vsd; }
        L += Lc;
        A += Ac;
    }
    ctx[bh * HD + t] = A / L;
}

extern "C" void kernel_launch(void* const* d_in, const int* in_sizes, int n_in,
                              void* d_out, int out_size, void* d_ws, size_t ws_size,
                              hipStream_t stream) {
    const float* hs   = (const float*)d_in[0];
    const float* pk   = (const float*)d_in[1];
    const float* pv   = (const float*)d_in[2];
    const float* mask = (const float*)d_in[3];
    const int*   cpos = (const int*)d_in[4];
    const float* Wq   = (const float*)d_in[5];
    const float* bq   = (const float*)d_in[6];
    const float* Wk   = (const float*)d_in[7];
    const float* bk   = (const float*)d_in[8];
    const float* Wv   = (const float*)d_in[9];
    const float* bv   = (const float*)d_in[10];
    const float* Wo   = (const float*)d_in[11];
    const float* bo   = (const float*)d_in[12];

    float* out_attn = (float*)d_out;                 // 16384
    float* kout = out_attn + BATCH * HID;            // 67108864
    float* vout = kout + KV_ELEMS;                   // 67108864

    float* ws    = (float*)d_ws;
    float* qkv   = ws;              // 49152
    float* ctx   = ws + 49152;      // 16384
    float* apart = ws + 65536;      // 256*8*68 = 139264

    // q,k,v projections (single-pass GEMV, deterministic intra-wave reduce)
    gemv3<<<dim3(768), 256, 0, stream>>>(hs, Wq, Wk, Wv, bq, bk, bv, qkv);

    // fused cache-copy + flash-decode attention (pure stream, stale row pos)
    attn_fused<<<dim3(256, NCHUNK), 256, 0, stream>>>(qkv, pk, pv, mask,
                                                      kout, vout, apart);
    // fix row pos (cache + partials) and merge chunks
    merge_fix<<<dim3(256), 64, 0, stream>>>(qkv, pk, pv, mask, cpos,
                                            kout, vout, apart, ctx);

    // output projection
    gemv3<<<dim3(256), 256, 0, stream>>>(ctx, Wo, Wo, Wo, bo, bo, bo, out_attn);
}

// Round 4
// 219.566 us; speedup vs baseline: 1.0618x; 1.0149x over previous
//
#include <hip/hip_runtime.h>
#include <hip/hip_bf16.h>

#define BATCH 16
#define SEQL  4096
#define NH    16
#define HD    64
#define HID   1024
#define NCHUNK 8
#define CHUNK  (SEQL / NCHUNK)   // 512
#define KV_ELEMS (BATCH * NH * SEQL * HD)  // 67108864
#define PSTRIDE 68               // partial record: [0]=L, [1..64]=A
#define C2 0.1803368801f         // 0.125 * log2(e)

typedef float f4 __attribute__((ext_vector_type(4)));

// ---------------------------------------------------------------------------
// Kernel 1: single-pass batched GEMV.  out[w][b][o] = x[b][:] . W[o][:] + bias
//   grid = nW*256 blocks; block = 256 (4 output cols x 64 lanes).
// ---------------------------------------------------------------------------
__global__ __launch_bounds__(256) void gemv3(
    const float* __restrict__ x,    // [16][1024]
    const float* __restrict__ W0, const float* __restrict__ W1,
    const float* __restrict__ W2,
    const float* __restrict__ b0, const float* __restrict__ b1,
    const float* __restrict__ b2,
    float* __restrict__ out)        // [nW][16][1024]
{
    __shared__ float xs[BATCH * HID];   // 64 KB
    const int t = threadIdx.x;
    {
        const f4* src = (const f4*)x;
        f4* dst = (f4*)xs;
        #pragma unroll
        for (int i = 0; i < (BATCH * HID / 4) / 256; ++i)
            dst[t + i * 256] = src[t + i * 256];
    }
    __syncthreads();

    const int which = blockIdx.x >> 8;
    const int ob    = (blockIdx.x & 255) << 2;
    const float* W    = (which == 0) ? W0 : ((which == 1) ? W1 : W2);
    const float* bias = (which == 0) ? b0 : ((which == 1) ? b1 : b2);
    const int col = t >> 6, lane = t & 63;
    const int o = ob + col;
    const float* wrow = W + (size_t)o * HID;

    float acc[BATCH];
    #pragma unroll
    for (int b = 0; b < BATCH; ++b) acc[b] = 0.f;

    #pragma unroll
    for (int i = 0; i < 4; ++i) {
        const int k = (lane << 2) + (i << 8);
        const f4 w4 = *(const f4*)&wrow[k];
        #pragma unroll
        for (int b = 0; b < BATCH; ++b) {
            const f4 h4 = *(const f4*)&xs[b * HID + k];
            acc[b] += w4.x * h4.x + w4.y * h4.y + w4.z * h4.z + w4.w * h4.w;
        }
    }

    #pragma unroll
    for (int b = 0; b < BATCH; ++b) {
        #pragma unroll
        for (int sh = 1; sh < 64; sh <<= 1)
            acc[b] += __shfl_xor(acc[b], sh);
    }
    if (lane == 0) {
        const float bb = bias[o];
        #pragma unroll
        for (int b = 0; b < BATCH; ++b)
            out[which * (BATCH * HID) + b * HID + o] = acc[b] + bb;
    }
}

// ---------------------------------------------------------------------------
// Kernel 2: fused cache-copy + flash-decode partial attention.
//   grid = (256 (b,h), 8 L-chunks), block = 256 (16 groups x 16 lanes).
//   Two-phase sub-loops: each 128-row sub-phase does a pure K copy+score
//   burst (p[] kept in registers, statically indexed), then a pure V
//   copy+accumulate burst -> 2 concurrent HBM streams per wave instead of 4,
//   8KB sequential bursts per buffer (copy-like page locality).
//   Row `pos` is streamed STALE and corrected exactly in merge_fix.
// ---------------------------------------------------------------------------
__global__ __launch_bounds__(256, 6) void attn_fused(
    const float* __restrict__ qkv,     // q @0
    const float* __restrict__ past_k,
    const float* __restrict__ past_v,
    const float* __restrict__ mask,    // [16][4096]
    float* __restrict__ kout,
    float* __restrict__ vout,
    float* __restrict__ part)          // [256][8][PSTRIDE]
{
    const int bh = blockIdx.x;         // 0..255
    const int c  = blockIdx.y;         // 0..7
    const int b  = bh >> 4;
    const int h  = bh & 15;
    const int t  = threadIdx.x;
    const int g  = t >> 4;             // group 0..15
    const int j  = t & 15;             // lane in group

    const f4 q4 = *(const f4*)&qkv[b * HID + h * HD + (j << 2)];

    const size_t base = (size_t)bh * (SEQL * HD);
    const float* __restrict__ pkb = past_k + base;
    const float* __restrict__ pvb = past_v + base;
    float* __restrict__ kob = kout + base;
    float* __restrict__ vob = vout + base;
    const float* __restrict__ mrow = mask + b * SEQL;

    float l = 0.f;
    f4 a4 = {0.f, 0.f, 0.f, 0.f};

    #pragma unroll 1
    for (int s = 0; s < CHUNK / 128; ++s) {   // 4 sub-phases of 128 rows
        const int r0 = c * CHUNK + s * 128 + g;       // rows r0 + u*16
        const int o0 = r0 * HD + (j << 2);

        // ---- K phase: stream copy + scores ----
        f4 kx[8];
        float am[8];
        #pragma unroll
        for (int u = 0; u < 8; ++u)
            kx[u] = __builtin_nontemporal_load((const f4*)(pkb + o0 + u * (16 * HD)));
        #pragma unroll
        for (int u = 0; u < 8; ++u)
            am[u] = mrow[r0 + u * 16];
        #pragma unroll
        for (int u = 0; u < 8; ++u)
            __builtin_nontemporal_store(kx[u], (f4*)(kob + o0 + u * (16 * HD)));

        float p[8];
        #pragma unroll
        for (int u = 0; u < 8; ++u) {
            float d = kx[u].x * q4.x + kx[u].y * q4.y
                    + kx[u].z * q4.z + kx[u].w * q4.w;
            d += __shfl_xor(d, 1);
            d += __shfl_xor(d, 2);
            d += __shfl_xor(d, 4);
            d += __shfl_xor(d, 8);
            float pe = exp2f(d * C2);
            p[u] = (am[u] > 0.f) ? pe : 0.f;
            l += p[u];
        }

        // ---- V phase: stream copy + weighted accumulate ----
        f4 vx[8];
        #pragma unroll
        for (int u = 0; u < 8; ++u)
            vx[u] = __builtin_nontemporal_load((const f4*)(pvb + o0 + u * (16 * HD)));
        #pragma unroll
        for (int u = 0; u < 8; ++u)
            __builtin_nontemporal_store(vx[u], (f4*)(vob + o0 + u * (16 * HD)));
        #pragma unroll
        for (int u = 0; u < 8; ++u) {
            a4.x += p[u] * vx[u].x;
            a4.y += p[u] * vx[u].y;
            a4.z += p[u] * vx[u].z;
            a4.w += p[u] * vx[u].w;
        }
    }

    // merge the 16 group states (straight sums — fixed-shift softmax)
    __shared__ float sl_[16];
    __shared__ float sa[16][64];
    if (j == 0) sl_[g] = l;
    *(f4*)&sa[g][(j << 2)] = a4;
    __syncthreads();

    float* pr = part + ((size_t)bh * NCHUNK + c) * PSTRIDE;
    if (t < 64) {
        float A = 0.f;
        #pragma unroll
        for (int gg = 0; gg < 16; ++gg) A += sa[gg][t];
        pr[1 + t] = A;
    } else if (t == 64) {
        float L = 0.f;
        #pragma unroll
        for (int gg = 0; gg < 16; ++gg) L += sl_[gg];
        pr[0] = L;
    }
}

// ---------------------------------------------------------------------------
// Kernel 3: per (b,h): overwrite cache row `pos` with the new k/v, correct
//           the affected chunk partial (remove stale row term, add new one),
//           then merge all chunk partials -> ctx. Block = 64 threads = 1 wave.
// ---------------------------------------------------------------------------
__global__ __launch_bounds__(64) void merge_fix(
    const float* __restrict__ qkv,
    const float* __restrict__ past_k,
    const float* __restrict__ past_v,
    const float* __restrict__ mask,
    const int*   __restrict__ cpos,
    float* __restrict__ kout,
    float* __restrict__ vout,
    const float* __restrict__ part,
    float* __restrict__ ctx)
{
    const int bh = blockIdx.x;
    const int b = bh >> 4, h = bh & 15;
    const int t = threadIdx.x;          // 0..63 (= head dim)
    const int pos = cpos[b];

    const size_t rowoff = (size_t)bh * (SEQL * HD) + (size_t)pos * HD + t;
    const int qo = b * HID + h * HD + t;
    const float qd  = qkv[qo];
    const float knd = qkv[BATCH * HID + qo];
    const float vnd = qkv[2 * BATCH * HID + qo];
    const float ksd = past_k[rowoff];
    const float vsd = past_v[rowoff];

    // overwrite caches at pos with the new row
    kout[rowoff] = knd;
    vout[rowoff] = vnd;

    // stale & new scores via full-wave reduce
    float dst = qd * ksd, dnw = qd * knd;
    #pragma unroll
    for (int sh = 1; sh < 64; sh <<= 1) {
        dst += __shfl_xor(dst, sh);
        dnw += __shfl_xor(dnw, sh);
    }
    const float am = mask[b * SEQL + pos];
    float ps = 0.f, pn = 0.f;
    if (am > 0.f) { ps = exp2f(dst * C2); pn = exp2f(dnw * C2); }

    const int cc0 = pos / CHUNK;
    float L = 0.f, A = 0.f;
    #pragma unroll
    for (int cc = 0; cc < NCHUNK; ++cc) {
        const float* pr = part + ((size_t)bh * NCHUNK + cc) * PSTRIDE;
        float Lc = pr[0];
        float Ac = pr[1 + t];
        if (cc == cc0) { Lc += pn - ps; Ac += pn * vnd - ps * vsd; }
        L += Lc;
        A += Ac;
    }
    ctx[bh * HD + t] = A / L;
}

extern "C" void kernel_launch(void* const* d_in, const int* in_sizes, int n_in,
                              void* d_out, int out_size, void* d_ws, size_t ws_size,
                              hipStream_t stream) {
    const float* hs   = (const float*)d_in[0];
    const float* pk   = (const float*)d_in[1];
    const float* pv   = (const float*)d_in[2];
    const float* mask = (const float*)d_in[3];
    const int*   cpos = (const int*)d_in[4];
    const float* Wq   = (const float*)d_in[5];
    const float* bq   = (const float*)d_in[6];
    const float* Wk   = (const float*)d_in[7];
    const float* bk   = (const float*)d_in[8];
    const float* Wv   = (const float*)d_in[9];
    const float* bv   = (const float*)d_in[10];
    const float* Wo   = (const float*)d_in[11];
    const float* bo   = (const float*)d_in[12];

    float* out_attn = (float*)d_out;                 // 16384
    float* kout = out_attn + BATCH * HID;            // 67108864
    float* vout = kout + KV_ELEMS;                   // 67108864

    float* ws    = (float*)d_ws;
    float* qkv   = ws;              // 49152
    float* ctx   = ws + 49152;      // 16384
    float* apart = ws + 65536;      // 256*8*68 = 139264

    // q,k,v projections (single-pass GEMV, deterministic intra-wave reduce)
    gemv3<<<dim3(768), 256, 0, stream>>>(hs, Wq, Wk, Wv, bq, bk, bv, qkv);

    // fused cache-copy + flash-decode attention (two-phase streaming)
    attn_fused<<<dim3(256, NCHUNK), 256, 0, stream>>>(qkv, pk, pv, mask,
                                                      kout, vout, apart);
    // fix row pos (cache + partials) and merge chunks
    merge_fix<<<dim3(256), 64, 0, stream>>>(qkv, pk, pv, mask, cpos,
                                            kout, vout, apart, ctx);

    // output projection
    gemv3<<<dim3(256), 256, 0, stream>>>(ctx, Wo, Wo, Wo, bo, bo, bo, out_attn);
}